// Round 2
// baseline (574.678 us; speedup 1.0000x reference)
//
#include <hip/hip_runtime.h>

#define D 128
#define BN_EPS 1e-5f
#define NSUB 1024
#define CAP2 2048

typedef __attribute__((ext_vector_type(8))) short short8;   // 8 x bf16 (4 VGPRs)
typedef __attribute__((ext_vector_type(4))) float floatx4;  // MFMA accumulator

__device__ __forceinline__ float bf2f(unsigned short u) {
    unsigned int x = ((unsigned int)u) << 16;
    return __builtin_bit_cast(float, x);
}
__device__ __forceinline__ unsigned short f2bf(float f) {
    unsigned int x = __builtin_bit_cast(unsigned int, f);
    x = x + 0x7FFFu + ((x >> 16) & 1u);  // round-to-nearest-even
    return (unsigned short)(x >> 16);
}
// exact floor(x / N) for x < 2^27 via host magic M = 2^44/N + 1 (N < 2^17)
__device__ __forceinline__ int magdiv(unsigned int x, unsigned long long magic) {
    return (int)(((unsigned long long)x * magic) >> 44);
}

// ---------------------------------------------------------------------------
// Merged setup: node_init + comb + pack_w1 + pack_w2 (all independent of CSR).
__global__ __launch_bounds__(256)
void setup_kernel(const int* __restrict__ x, const int* __restrict__ z,
                  const float* __restrict__ atom_emb, const float* __restrict__ z_emb,
                  unsigned short* __restrict__ hb, int N, int nbNode,
                  const float* __restrict__ bond_emb, unsigned short* __restrict__ comb,
                  const float* __restrict__ W1, unsigned short* __restrict__ w1p,
                  const float* __restrict__ W2, unsigned short* __restrict__ w2p) {
    const int b = blockIdx.x;
    const int tid = threadIdx.x;
    if (b < nbNode) {
        // ---- node_init: hb0 = bf16( sum_f atom_emb[f,x[n,f],:] + z_emb[z[n],:] )
        int gid = b * 256 + tid;
        int node = gid >> 5;
        if (node >= N) return;
        int d0 = (gid & 31) * 4;
        float4 acc = *(const float4*)(z_emb + (size_t)z[node] * D + d0);
#pragma unroll
        for (int f = 0; f < 9; ++f) {
            int v = x[node * 9 + f];
            const float4 t = *(const float4*)(atom_emb + (size_t)(f * 119 + v) * D + d0);
            acc.x += t.x; acc.y += t.y; acc.z += t.z; acc.w += t.w;
        }
        ushort4 o;
        o.x = f2bf(acc.x); o.y = f2bf(acc.y); o.z = f2bf(acc.z); o.w = f2bf(acc.w);
        *(ushort4*)(hb + (size_t)node * D + d0) = o;
    } else if (b < nbNode + 216) {
        // ---- comb[layer][c][d] = bf16(b0[a0][d]+b1[a1][d]+b2[a2][d]); 2*27648 elems
        int t = (b - nbNode) * 256 + tid;
        int layer = t / (216 * D);
        int idx = t - layer * (216 * D);
        int c = idx >> 7, d = idx & 127;
        int a0 = c / 36, a1 = (c / 6) % 6, a2 = c % 6;
        const float* bb = bond_emb + (size_t)layer * 3 * 6 * D;
        float v = bb[(0 * 6 + a0) * D + d] + bb[(1 * 6 + a1) * D + d] + bb[(2 * 6 + a2) * D + d];
        comb[(size_t)layer * 216 * D + idx] = f2bf(v);
    } else {
        // ---- pack W [K][NCOLS] fp32 row-major -> fragment-linear bf16
        int isW2 = (b >= nbNode + 216 + 256);
        int t = (b - nbNode - 216 - (isW2 ? 256 : 0)) * 256 + tid;
        int layer = t >> 15;           // total = 32768 per layer for both
        int idx = t & 32767;
        int logN = isW2 ? 7 : 8;
        int NCOLS = 1 << logN;
        int k = idx >> logN, n = idx & (NCOLS - 1);
        int k0 = k >> 5, kq = k & 31, q = kq >> 3, j = kq & 7;
        int tt = n >> 4, ln = n & 15;
        size_t dest = (((size_t)k0 * (NCOLS >> 4) + tt) << 9) + ((q << 4) + ln) * 8 + j;
        const float* W = (isW2 ? W2 : W1) + (size_t)layer * 32768;
        unsigned short* Wp = (isW2 ? w2p : w1p) + (size_t)layer * 32768;
        Wp[dest] = f2bf(W[idx]);
    }
}

// ---------------------------------------------------------------------------
// Level-1 partition: edges -> 8 per-dst-slice int2{dst, pay} lists.
// pay = src | comb_idx<<17 (25 bits). Wave-private counters; magic div.
__global__ __launch_bounds__(256)
void partition1_kernel(const int* __restrict__ ei, const int* __restrict__ ea,
                       int2* __restrict__ l1, int* __restrict__ tail1,
                       int E, unsigned long long magic, int capE, int ntiles, int nblocks) {
    __shared__ int lcnt[4][8], lbase[4][8];
    const int tid = threadIdx.x;
    const int wid = tid >> 6;
    for (int tile = blockIdx.x; tile < ntiles; tile += nblocks) {
        const int tb = tile * 4096;
        if (tid < 32) ((int*)lcnt)[tid] = 0;
        __syncthreads();
        int mydst[16], mypay[16];
#pragma unroll
        for (int j = 0; j < 16; ++j) {
            int e = tb + j * 256 + tid;
            if (e < E) {
                int dst = ei[E + e];
                int c = (ea[3 * e] * 6 + ea[3 * e + 1]) * 6 + ea[3 * e + 2];
                mydst[j] = dst;
                mypay[j] = ei[e] | (c << 17);
                atomicAdd(&lcnt[wid][magdiv((unsigned)dst * 8u, magic)], 1);
            } else {
                mydst[j] = -1;
            }
        }
        __syncthreads();
        if (tid < 32) {
            int w = tid >> 3, s = tid & 7;
            lbase[w][s] = atomicAdd(&tail1[s], lcnt[w][s]);
            lcnt[w][s] = 0;
        }
        __syncthreads();
#pragma unroll
        for (int j = 0; j < 16; ++j) {
            if (mydst[j] >= 0) {
                int s = magdiv((unsigned)mydst[j] * 8u, magic);
                int pos = lbase[wid][s] + atomicAdd(&lcnt[wid][s], 1);
                if (pos < capE) l1[(size_t)s * capE + pos] = make_int2(mydst[j], mypay[j]);
            }
        }
        __syncthreads();
    }
}

// ---------------------------------------------------------------------------
// Level-2 partition: slice list -> 128 sub-slice lists (4 B packed entries:
// pay | local_dst<<25). Sub-slice k covers nodes [ceil(kN/1024), ceil((k+1)N/1024)).
__global__ __launch_bounds__(256)
void partition2_kernel(const int2* __restrict__ l1, const int* __restrict__ tail1,
                       unsigned int* __restrict__ subL, int* __restrict__ tail2,
                       int N, unsigned long long magic, int capE, int G) {
    __shared__ int lcnt[128], lbase[128];
    const int s = blockIdx.x & 7;
    const int g = blockIdx.x >> 3;
    const int tid = threadIdx.x;
    const int len = min(tail1[s], capE);
    const int2* src = l1 + (size_t)s * capE;
    for (int tb = g * 4096; tb < len; tb += G * 4096) {
        if (tid < 128) lcnt[tid] = 0;
        __syncthreads();
        int2 e[16];
        int sub[16];
#pragma unroll
        for (int j = 0; j < 16; ++j) {
            int i = tb + j * 256 + tid;
            if (i < len) {
                e[j] = src[i];
                sub[j] = magdiv((unsigned)e[j].x * 1024u, magic) - (s << 7);
                atomicAdd(&lcnt[sub[j]], 1);
            } else {
                sub[j] = -1;
            }
        }
        __syncthreads();
        if (tid < 128) {
            lbase[tid] = atomicAdd(&tail2[(s << 7) + tid], lcnt[tid]);
            lcnt[tid] = 0;
        }
        __syncthreads();
#pragma unroll
        for (int j = 0; j < 16; ++j) {
            if (sub[j] >= 0) {
                int k = (s << 7) + sub[j];
                int lo = (int)(((long long)k * N + 1023) >> 10);
                int pos = lbase[sub[j]] + atomicAdd(&lcnt[sub[j]], 1);
                if (pos < CAP2)
                    subL[(size_t)k * CAP2 + pos] =
                        (unsigned int)e[j].y | ((unsigned int)(e[j].x - lo) << 25);
            }
        }
        __syncthreads();
    }
}

// ---------------------------------------------------------------------------
// Exclusive scan of 1024 sub-slice tails -> subbase; offsets[N] = E.
__global__ __launch_bounds__(1024)
void subscan_kernel(const int* __restrict__ tail2, int* __restrict__ subbase,
                    int* __restrict__ offsets, int N) {
    const int tid = threadIdx.x, lane = tid & 63, wid = tid >> 6;
    int v = min(tail2[tid], CAP2);
    int s = v;
#pragma unroll
    for (int off = 1; off < 64; off <<= 1) {
        int t = __shfl_up(s, off, 64);
        if (lane >= off) s += t;
    }
    __shared__ int ws[16];
    if (lane == 63) ws[wid] = s;
    __syncthreads();
    if (wid == 0) {
        int w = (lane < 16) ? ws[lane] : 0;
#pragma unroll
        for (int off = 1; off < 16; off <<= 1) {
            int t = __shfl_up(w, off, 64);
            if (lane >= off) w += t;
        }
        if (lane < 16) ws[lane] = w;
    }
    __syncthreads();
    int excl = (wid ? ws[wid - 1] : 0) + s - v;
    subbase[tid] = excl;
    if (tid == 1023) offsets[N] = excl + v;
}

// ---------------------------------------------------------------------------
// One block per sub-slice: LDS counting sort -> contiguous coalesced writes of
// bucket + offsets. No global scatter, no global cursor atomics.
__global__ __launch_bounds__(256)
void csr_sort_kernel(const unsigned int* __restrict__ subL, const int* __restrict__ tail2,
                     const int* __restrict__ subbase, int* __restrict__ offsets,
                     int* __restrict__ bucket, int N) {
    const int k = blockIdx.x;
    const int tid = threadIdx.x, lane = tid & 63, wid = tid >> 6;
    const int len = min(tail2[k], CAP2);
    const int base = subbase[k];
    const int lo = (int)(((long long)k * N + 1023) >> 10);
    const int hi = (int)(((long long)(k + 1) * N + 1023) >> 10);
    const int nn = hi - lo;  // <= 128
    __shared__ int cnt[128], loff[128], wsum[4];
    __shared__ unsigned int sorted[CAP2];
    const unsigned int* src = subL + (size_t)k * CAP2;

    if (tid < 128) cnt[tid] = 0;
    __syncthreads();
    for (int i = tid; i < len; i += 256) atomicAdd(&cnt[src[i] >> 25], 1);
    __syncthreads();
    // exclusive scan of cnt[0..127] (first 2 waves meaningful)
    int v = (tid < 128) ? cnt[tid] : 0;
    int s = v;
#pragma unroll
    for (int off = 1; off < 64; off <<= 1) {
        int t = __shfl_up(s, off, 64);
        if (lane >= off) s += t;
    }
    if (lane == 63) wsum[wid] = s;
    __syncthreads();
    if (tid < 128) loff[tid] = ((wid == 1) ? wsum[0] : 0) + s - v;
    __syncthreads();
    if (tid < nn) offsets[lo + tid] = base + loff[tid];
    if (tid < 128) cnt[tid] = 0;
    __syncthreads();
    for (int i = tid; i < len; i += 256) {
        unsigned int e = src[i];
        int ld = e >> 25;
        int pos = loff[ld] + atomicAdd(&cnt[ld], 1);
        sorted[pos] = e & 0x1FFFFFFu;
    }
    __syncthreads();
    for (int i = tid; i < len; i += 256) bucket[base + i] = (int)sorted[i];
}

// ---------------------------------------------------------------------------
// pre[n] = bf16( (1+eps)*h[n] + sum_{e in in(n)} relu(h[src_e] + comb[c_e]) )
__global__ __launch_bounds__(256)
void gather_reduce_kernel(const int* __restrict__ offsets, const int* __restrict__ bucket,
                          const unsigned short* __restrict__ comb,
                          const unsigned short* __restrict__ hb,
                          const float* __restrict__ eps_l,
                          unsigned short* __restrict__ pre, int N) {
    int gid = blockIdx.x * blockDim.x + threadIdx.x;
    int node = gid >> 4;
    if (node >= N) return;
    int d0 = (gid & 15) * 8;

    union U8 { int4 i; unsigned short u[8]; };
    float s = 1.0f + eps_l[0];
    float a[8];
    {
        U8 hv; hv.i = *(const int4*)(hb + (size_t)node * D + d0);
#pragma unroll
        for (int j = 0; j < 8; ++j) a[j] = bf2f(hv.u[j]) * s;
    }
    const int beg = offsets[node], end = offsets[node + 1];
    for (int p = beg; p < end; p += 4) {
        int rem = end - p;
        int pk0 = bucket[p];
        int pk1 = bucket[rem > 1 ? p + 1 : p];
        int pk2 = bucket[rem > 2 ? p + 2 : p];
        int pk3 = bucket[rem > 3 ? p + 3 : p];
        U8 h0, h1, h2, h3, c0, c1, c2, c3;
        h0.i = *(const int4*)(hb + (size_t)(pk0 & 0x1FFFF) * D + d0);
        c0.i = *(const int4*)(comb + (size_t)((pk0 >> 17) & 0xFF) * D + d0);
        h1.i = *(const int4*)(hb + (size_t)(pk1 & 0x1FFFF) * D + d0);
        c1.i = *(const int4*)(comb + (size_t)((pk1 >> 17) & 0xFF) * D + d0);
        h2.i = *(const int4*)(hb + (size_t)(pk2 & 0x1FFFF) * D + d0);
        c2.i = *(const int4*)(comb + (size_t)((pk2 >> 17) & 0xFF) * D + d0);
        h3.i = *(const int4*)(hb + (size_t)(pk3 & 0x1FFFF) * D + d0);
        c3.i = *(const int4*)(comb + (size_t)((pk3 >> 17) & 0xFF) * D + d0);
#pragma unroll
        for (int j = 0; j < 8; ++j) a[j] += fmaxf(bf2f(h0.u[j]) + bf2f(c0.u[j]), 0.0f);
        if (rem > 1) {
#pragma unroll
            for (int j = 0; j < 8; ++j) a[j] += fmaxf(bf2f(h1.u[j]) + bf2f(c1.u[j]), 0.0f);
        }
        if (rem > 2) {
#pragma unroll
            for (int j = 0; j < 8; ++j) a[j] += fmaxf(bf2f(h2.u[j]) + bf2f(c2.u[j]), 0.0f);
        }
        if (rem > 3) {
#pragma unroll
            for (int j = 0; j < 8; ++j) a[j] += fmaxf(bf2f(h3.u[j]) + bf2f(c3.u[j]), 0.0f);
        }
    }
    U8 o;
#pragma unroll
    for (int j = 0; j < 8; ++j) o.u[j] = f2bf(a[j]);
    *(int4*)(pre + (size_t)node * D + d0) = o.i;
}

// ---------------------------------------------------------------------------
// MFMA GEMM, B staged in LDS (2 x 32KB phases), A prefetched; fused stats.
template <int K, int NCOLS, int TRANSFORM, int OUTBF>
__global__ __launch_bounds__(256)
void mfma_gemm_kernel(const unsigned short* __restrict__ A,
                      const unsigned short* __restrict__ Wp,
                      const float* __restrict__ bias,
                      const float* __restrict__ tscale, const float* __restrict__ tshift,
                      unsigned short* __restrict__ Cbf, float* __restrict__ Cf,
                      float* __restrict__ partial, int M) {
    constexpr int NT = NCOLS / 16;
    constexpr int NCHUNK = K / 32;
    constexpr int CPP = NCHUNK / 2;
    __shared__ unsigned short Ws[16384];
    __shared__ float red[NCOLS * 2];

    const int tid = threadIdx.x;
    const int wave = tid >> 6, lane = tid & 63;
    const int quad = lane >> 4, ln = lane & 15;
    const int m_base = blockIdx.x * 64 + wave * 16;
    int arow = m_base + ln;
    if (arow >= M) arow = M - 1;
    const int kq = quad * 8;

    int4 araw[NCHUNK];
#pragma unroll
    for (int c = 0; c < NCHUNK; ++c)
        araw[c] = *(const int4*)(A + (size_t)arow * K + c * 32 + kq);

    for (int i = tid; i < NCOLS * 2; i += 256) red[i] = 0.f;

    floatx4 acc[NT];
#pragma unroll
    for (int t = 0; t < NT; ++t) acc[t] = (floatx4){0.f, 0.f, 0.f, 0.f};

#pragma unroll
    for (int ph = 0; ph < 2; ++ph) {
        if (ph) __syncthreads();
#pragma unroll
        for (int i = 0; i < 16384; i += 2048)
            *(int4*)&Ws[i + tid * 8] = *(const int4*)&Wp[ph * 16384 + i + tid * 8];
        __syncthreads();
#pragma unroll
        for (int cc = 0; cc < CPP; ++cc) {
            const int c = ph * CPP + cc;
            short8 afrag;
            if constexpr (TRANSFORM) {
                union { int4 i; unsigned short u[8]; } raw;
                raw.i = araw[c];
                const int kb = c * 32 + kq;
                float4 sc0 = *(const float4*)(tscale + kb);
                float4 sc1 = *(const float4*)(tscale + kb + 4);
                float4 sh0 = *(const float4*)(tshift + kb);
                float4 sh1 = *(const float4*)(tshift + kb + 4);
                union { short8 v; unsigned short u[8]; } au;
                au.u[0] = f2bf(fmaxf(bf2f(raw.u[0]) * sc0.x + sh0.x, 0.f));
                au.u[1] = f2bf(fmaxf(bf2f(raw.u[1]) * sc0.y + sh0.y, 0.f));
                au.u[2] = f2bf(fmaxf(bf2f(raw.u[2]) * sc0.z + sh0.z, 0.f));
                au.u[3] = f2bf(fmaxf(bf2f(raw.u[3]) * sc0.w + sh0.w, 0.f));
                au.u[4] = f2bf(fmaxf(bf2f(raw.u[4]) * sc1.x + sh1.x, 0.f));
                au.u[5] = f2bf(fmaxf(bf2f(raw.u[5]) * sc1.y + sh1.y, 0.f));
                au.u[6] = f2bf(fmaxf(bf2f(raw.u[6]) * sc1.z + sh1.z, 0.f));
                au.u[7] = f2bf(fmaxf(bf2f(raw.u[7]) * sc1.w + sh1.w, 0.f));
                afrag = au.v;
            } else {
                afrag = __builtin_bit_cast(short8, araw[c]);
            }
#pragma unroll
            for (int t = 0; t < NT; ++t) {
                short8 bfrag = *(const short8*)&Ws[(((cc * NT) + t) << 9) + lane * 8];
                acc[t] = __builtin_amdgcn_mfma_f32_16x16x32_bf16(afrag, bfrag, acc[t], 0, 0, 0);
            }
        }
    }

#pragma unroll
    for (int t = 0; t < NT; ++t) {
        int col = t * 16 + ln;
        float bv = bias[col];
        float sv = 0.f, qv = 0.f;
#pragma unroll
        for (int r = 0; r < 4; ++r) {
            int row = m_base + quad * 4 + r;
            if (row < M) {
                float v = acc[t][r] + bv;
                sv += v; qv += v * v;
                if constexpr (OUTBF) Cbf[(size_t)row * NCOLS + col] = f2bf(v);
                else                 Cf[(size_t)row * NCOLS + col] = v;
            }
        }
        sv += __shfl_xor(sv, 16, 64); sv += __shfl_xor(sv, 32, 64);
        qv += __shfl_xor(qv, 16, 64); qv += __shfl_xor(qv, 32, 64);
        if (quad == 0) {
            atomicAdd(&red[col], sv);
            atomicAdd(&red[NCOLS + col], qv);
        }
    }
    __syncthreads();
    float* pout = partial + (size_t)blockIdx.x * (NCOLS * 2);
    for (int i = tid; i < NCOLS * 2; i += 256) pout[i] = red[i];
}

// ---------------------------------------------------------------------------
template <int NCOLS>
__global__ __launch_bounds__(256)
void reduce_stats_kernel(const float* __restrict__ partial, int nb,
                         const float* __restrict__ g, const float* __restrict__ b,
                         float* __restrict__ scale, float* __restrict__ shift, float invN) {
    const int col = blockIdx.x;
    const int tid = threadIdx.x;
    float s = 0.f, q = 0.f;
    for (int bb = tid; bb < nb; bb += 256) {
        const float* p = partial + (size_t)bb * (NCOLS * 2);
        s += p[col];
        q += p[NCOLS + col];
    }
#pragma unroll
    for (int off = 32; off > 0; off >>= 1) {
        s += __shfl_xor(s, off, 64);
        q += __shfl_xor(q, off, 64);
    }
    __shared__ float ws[4], wq[4];
    if ((tid & 63) == 0) { ws[tid >> 6] = s; wq[tid >> 6] = q; }
    __syncthreads();
    if (tid == 0) {
        s = ws[0] + ws[1] + ws[2] + ws[3];
        q = wq[0] + wq[1] + wq[2] + wq[3];
        float mean = s * invN;
        float var = q * invN - mean * mean;
        float inv = 1.0f / sqrtf(var + BN_EPS);
        float sc = g[col] * inv;
        scale[col] = sc;
        shift[col] = b[col] - mean * sc;
    }
}

// ---------------------------------------------------------------------------
// mode 0: hb = bf16(relu(bn(Xb bf16)))   mode 1: h = bn(Xf fp32) fp32 (final)
__global__ void bn_apply_kernel(const float* __restrict__ Xf, const unsigned short* __restrict__ Xb,
                                float* __restrict__ Yf, unsigned short* __restrict__ Yb,
                                const float* __restrict__ scale, const float* __restrict__ shift,
                                int N, int mode) {
    int gid = blockIdx.x * blockDim.x + threadIdx.x;
    int node = gid >> 5;
    if (node >= N) return;
    int d0 = (gid & 31) * 4;
    float4 v;
    if (mode == 0) {
        ushort4 b = *(const ushort4*)(Xb + (size_t)node * D + d0);
        v.x = bf2f(b.x); v.y = bf2f(b.y); v.z = bf2f(b.z); v.w = bf2f(b.w);
    } else {
        v = *(const float4*)(Xf + (size_t)node * D + d0);
    }
    float4 sc = *(const float4*)(scale + d0);
    float4 sh = *(const float4*)(shift + d0);
    float4 o;
    o.x = v.x * sc.x + sh.x;
    o.y = v.y * sc.y + sh.y;
    o.z = v.z * sc.z + sh.z;
    o.w = v.w * sc.w + sh.w;
    if (mode == 0) {
        ushort4 ob;
        ob.x = f2bf(fmaxf(o.x, 0.f));
        ob.y = f2bf(fmaxf(o.y, 0.f));
        ob.z = f2bf(fmaxf(o.z, 0.f));
        ob.w = f2bf(fmaxf(o.w, 0.f));
        *(ushort4*)(Yb + (size_t)node * D + d0) = ob;
    } else {
        *(float4*)(Yf + (size_t)node * D + d0) = o;
    }
}

// ---------------------------------------------------------------------------
extern "C" void kernel_launch(void* const* d_in, const int* in_sizes, int n_in,
                              void* d_out, int out_size, void* d_ws, size_t ws_size,
                              hipStream_t stream) {
    const int*   x        = (const int*)d_in[0];
    const int*   z        = (const int*)d_in[1];
    const int*   ei       = (const int*)d_in[2];
    const int*   ea       = (const int*)d_in[3];
    const float* atom_emb = (const float*)d_in[4];
    const float* z_emb    = (const float*)d_in[5];
    const float* bond_emb = (const float*)d_in[6];
    const float* eps      = (const float*)d_in[7];
    const float* W1       = (const float*)d_in[8];
    const float* b1       = (const float*)d_in[9];
    const float* g1       = (const float*)d_in[10];
    const float* be1      = (const float*)d_in[11];
    const float* W2       = (const float*)d_in[12];
    const float* b2       = (const float*)d_in[13];
    const float* bng      = (const float*)d_in[14];
    const float* bnb      = (const float*)d_in[15];

    const int N = in_sizes[1];
    const int E = in_sizes[3] / 3;

    float* h = (float*)d_out;  // final [N,128] fp32

    const int ngb = (N + 63) / 64;   // GEMM grid
    const int capE = E / 8 + E / 64; // per-slice L1 list capacity (~60 sigma)
    const unsigned long long magic = ((1ULL << 44) / (unsigned int)N) + 1;  // exact for x < 2^27

    char* ws = (char*)d_ws;
    size_t off = 0;
    auto alloc = [&](size_t bytes) { void* p = ws + off; off += (bytes + 255) & ~(size_t)255; return p; };
    unsigned short* pre_bf = (unsigned short*)alloc((size_t)N * D * 2);      // 25.6 MB
    unsigned short* extra  = (unsigned short*)alloc((size_t)N * D * 2);      // 25.6 MB (out2 tail)
    (void)extra;
    float* out2 = (float*)pre_bf;                // fp32 spans pre_bf+extra (layer 1)
    unsigned short* out2_bf = pre_bf;            // bf16 fits pre_bf alone (layer 0)
    unsigned short* out1_bf = (unsigned short*)alloc((size_t)N * 2 * D * 2); // 51.2 MB
    unsigned short* hb      = (unsigned short*)alloc((size_t)N * D * 2);     // 25.6 MB
    int* offsets = (int*)alloc((size_t)(N + 1) * 4);
    int* bucket  = (int*)alloc((size_t)E * 4);
    int2* l1     = (int2*)alloc((size_t)8 * capE * 8);           // ~14.4 MB
    unsigned int* subL = (unsigned int*)alloc((size_t)NSUB * CAP2 * 4); // 8 MB
    int* subbase = (int*)alloc(NSUB * 4);
    float* stats = (float*)alloc(1024 * 4);
    float* partial1 = (float*)alloc((size_t)ngb * 512 * 4);  // 3.2 MB
    float* partial2 = (float*)alloc((size_t)ngb * 256 * 4);  // 1.6 MB
    unsigned short* w1p  = (unsigned short*)alloc((size_t)2 * D * 2 * D * 2);
    unsigned short* w2p  = (unsigned short*)alloc((size_t)2 * 2 * D * D * 2);
    unsigned short* comb = (unsigned short*)alloc((size_t)2 * 216 * D * 2);
    // transient tails alias out1_bf (dead until first GEMM1 write)
    int* tail1 = (int*)out1_bf;   // 8 ints
    int* tail2 = tail1 + 8;       // 1024 ints

    float* scale1 = stats;          // 256
    float* shift1 = stats + 256;    // 256
    float* scale2 = stats + 512;    // 128
    float* shift2 = stats + 640;    // 128

    const float invN = 1.0f / (float)N;
    const int ntiles = (E + 4095) / 4096;
    const int nbNode = (N * 32 + 255) / 256;

    // --- CSR build: partition1 -> partition2 -> subscan -> LDS counting sort ---
    hipMemsetAsync(tail1, 0, (8 + NSUB) * sizeof(int), stream);
    partition1_kernel<<<256, 256, 0, stream>>>(ei, ea, l1, tail1, E, magic, capE, ntiles, 256);
    partition2_kernel<<<256, 256, 0, stream>>>(l1, tail1, subL, tail2, N, magic, capE, 32);
    subscan_kernel<<<1, 1024, 0, stream>>>(tail2, subbase, offsets, N);
    csr_sort_kernel<<<NSUB, 256, 0, stream>>>(subL, tail2, subbase, offsets, bucket, N);

    // --- merged setup: node_init + comb + pack_w1 + pack_w2 ---
    setup_kernel<<<nbNode + 216 + 256 + 256, 256, 0, stream>>>(
        x, z, atom_emb, z_emb, hb, N, nbNode, bond_emb, comb, W1, w1p, W2, w2p);

    for (int l = 0; l < 2; ++l) {
        gather_reduce_kernel<<<(N * 16 + 255) / 256, 256, 0, stream>>>(
            offsets, bucket, comb + (size_t)l * 216 * D, hb, eps + l, pre_bf, N);

        mfma_gemm_kernel<128, 256, 0, 1><<<ngb, 256, 0, stream>>>(
            pre_bf, w1p + (size_t)l * D * 2 * D, b1 + (size_t)l * 2 * D,
            nullptr, nullptr, out1_bf, nullptr, partial1, N);
        reduce_stats_kernel<256><<<256, 256, 0, stream>>>(
            partial1, ngb, g1 + (size_t)l * 2 * D, be1 + (size_t)l * 2 * D,
            scale1, shift1, invN);

        if (l == 0) {
            // layer 0: out2 in bf16 (it is rounded to bf16 by bn_apply anyway)
            mfma_gemm_kernel<256, 128, 1, 1><<<ngb, 256, 0, stream>>>(
                out1_bf, w2p + (size_t)l * 2 * D * D, b2 + (size_t)l * D,
                scale1, shift1, out2_bf, nullptr, partial2, N);
        } else {
            mfma_gemm_kernel<256, 128, 1, 0><<<ngb, 256, 0, stream>>>(
                out1_bf, w2p + (size_t)l * 2 * D * D, b2 + (size_t)l * D,
                scale1, shift1, nullptr, out2, partial2, N);
        }
        reduce_stats_kernel<128><<<128, 256, 0, stream>>>(
            partial2, ngb, bng + (size_t)l * D, bnb + (size_t)l * D,
            scale2, shift2, invN);

        bn_apply_kernel<<<(N * 32 + 255) / 256, 256, 0, stream>>>(
            out2, out2_bf, h, hb, scale2, shift2, N, l == 0 ? 0 : 1);
    }
}

// Round 3
// 558.262 us; speedup vs baseline: 1.0294x; 1.0294x over previous
//
#include <hip/hip_runtime.h>

#define D 128
#define BN_EPS 1e-5f
#define NSUB 1024
#define CAP2 2048

typedef __attribute__((ext_vector_type(8))) short short8;   // 8 x bf16 (4 VGPRs)
typedef __attribute__((ext_vector_type(4))) float floatx4;  // MFMA accumulator

__device__ __forceinline__ float bf2f(unsigned short u) {
    unsigned int x = ((unsigned int)u) << 16;
    return __builtin_bit_cast(float, x);
}
__device__ __forceinline__ unsigned short f2bf(float f) {
    unsigned int x = __builtin_bit_cast(unsigned int, f);
    x = x + 0x7FFFu + ((x >> 16) & 1u);  // round-to-nearest-even
    return (unsigned short)(x >> 16);
}
// exact floor(x / N) for x < 2^27 via host magic M = 2^44/N + 1 (N < 2^17)
__device__ __forceinline__ int magdiv(unsigned int x, unsigned long long magic) {
    return (int)(((unsigned long long)x * magic) >> 44);
}

// ---------------------------------------------------------------------------
// Merged setup: node_init + comb + pack_w1 + pack_w2 (all independent of CSR).
__global__ __launch_bounds__(256)
void setup_kernel(const int* __restrict__ x, const int* __restrict__ z,
                  const float* __restrict__ atom_emb, const float* __restrict__ z_emb,
                  unsigned short* __restrict__ hb, int N, int nbNode,
                  const float* __restrict__ bond_emb, unsigned short* __restrict__ comb,
                  const float* __restrict__ W1, unsigned short* __restrict__ w1p,
                  const float* __restrict__ W2, unsigned short* __restrict__ w2p) {
    const int b = blockIdx.x;
    const int tid = threadIdx.x;
    if (b < nbNode) {
        // ---- node_init: hb0 = bf16( sum_f atom_emb[f,x[n,f],:] + z_emb[z[n],:] )
        int gid = b * 256 + tid;
        int node = gid >> 5;
        if (node >= N) return;
        int d0 = (gid & 31) * 4;
        float4 acc = *(const float4*)(z_emb + (size_t)z[node] * D + d0);
#pragma unroll
        for (int f = 0; f < 9; ++f) {
            int v = x[node * 9 + f];
            const float4 t = *(const float4*)(atom_emb + (size_t)(f * 119 + v) * D + d0);
            acc.x += t.x; acc.y += t.y; acc.z += t.z; acc.w += t.w;
        }
        ushort4 o;
        o.x = f2bf(acc.x); o.y = f2bf(acc.y); o.z = f2bf(acc.z); o.w = f2bf(acc.w);
        *(ushort4*)(hb + (size_t)node * D + d0) = o;
    } else if (b < nbNode + 216) {
        // ---- comb[layer][c][d] = bf16(b0[a0][d]+b1[a1][d]+b2[a2][d]); 2*27648 elems
        int t = (b - nbNode) * 256 + tid;
        int layer = t / (216 * D);
        int idx = t - layer * (216 * D);
        int c = idx >> 7, d = idx & 127;
        int a0 = c / 36, a1 = (c / 6) % 6, a2 = c % 6;
        const float* bb = bond_emb + (size_t)layer * 3 * 6 * D;
        float v = bb[(0 * 6 + a0) * D + d] + bb[(1 * 6 + a1) * D + d] + bb[(2 * 6 + a2) * D + d];
        comb[(size_t)layer * 216 * D + idx] = f2bf(v);
    } else {
        // ---- pack W [K][NCOLS] fp32 row-major -> fragment-linear bf16
        int isW2 = (b >= nbNode + 216 + 256);
        int t = (b - nbNode - 216 - (isW2 ? 256 : 0)) * 256 + tid;
        int layer = t >> 15;           // total = 32768 per layer for both
        int idx = t & 32767;
        int logN = isW2 ? 7 : 8;
        int NCOLS = 1 << logN;
        int k = idx >> logN, n = idx & (NCOLS - 1);
        int k0 = k >> 5, kq = k & 31, q = kq >> 3, j = kq & 7;
        int tt = n >> 4, ln = n & 15;
        size_t dest = (((size_t)k0 * (NCOLS >> 4) + tt) << 9) + ((q << 4) + ln) * 8 + j;
        const float* W = (isW2 ? W2 : W1) + (size_t)layer * 32768;
        unsigned short* Wp = (isW2 ? w2p : w1p) + (size_t)layer * 32768;
        Wp[dest] = f2bf(W[idx]);
    }
}

// ---------------------------------------------------------------------------
// Single-pass 1024-way partition: edges -> 1024 sub-slice lists directly.
// Packed entry: src(17) | comb_idx<<17 (8) | local_dst<<25 (7).
__global__ __launch_bounds__(256)
void partition_kernel(const int* __restrict__ ei, const int* __restrict__ ea,
                      unsigned int* __restrict__ subL, int* __restrict__ tail2,
                      int E, int N, unsigned long long magic, int ntiles, int nblocks) {
    __shared__ int lcnt[1024], lbase[1024];
    const int tid = threadIdx.x;
    for (int tile = blockIdx.x; tile < ntiles; tile += nblocks) {
        const int tb = tile * 4096;
#pragma unroll
        for (int i = 0; i < 4; ++i) lcnt[tid + i * 256] = 0;
        __syncthreads();
        int sub[16];
        unsigned int entry[16];
#pragma unroll
        for (int j = 0; j < 16; ++j) {
            int e = tb + j * 256 + tid;
            if (e < E) {
                int dst = ei[E + e];
                int c = (ea[3 * e] * 6 + ea[3 * e + 1]) * 6 + ea[3 * e + 2];
                int k = magdiv((unsigned)dst * 1024u, magic);
                int lo = (int)(((long long)k * N + 1023) >> 10);
                sub[j] = k;
                entry[j] = (unsigned int)ei[e] | ((unsigned int)c << 17) |
                           ((unsigned int)(dst - lo) << 25);
                atomicAdd(&lcnt[k], 1);
            } else {
                sub[j] = -1;
            }
        }
        __syncthreads();
#pragma unroll
        for (int i = 0; i < 4; ++i) {
            int k = tid + i * 256;
            int c = lcnt[k];
            if (c) lbase[k] = atomicAdd(&tail2[k], c);
            lcnt[k] = 0;
        }
        __syncthreads();
#pragma unroll
        for (int j = 0; j < 16; ++j) {
            if (sub[j] >= 0) {
                int k = sub[j];
                int pos = lbase[k] + atomicAdd(&lcnt[k], 1);
                if (pos < CAP2) subL[(size_t)k * CAP2 + pos] = entry[j];
            }
        }
        __syncthreads();
    }
}

// ---------------------------------------------------------------------------
// Exclusive scan of 1024 sub-slice tails -> subbase; offsets[N] = E.
__global__ __launch_bounds__(1024)
void subscan_kernel(const int* __restrict__ tail2, int* __restrict__ subbase,
                    int* __restrict__ offsets, int N) {
    const int tid = threadIdx.x, lane = tid & 63, wid = tid >> 6;
    int v = min(tail2[tid], CAP2);
    int s = v;
#pragma unroll
    for (int off = 1; off < 64; off <<= 1) {
        int t = __shfl_up(s, off, 64);
        if (lane >= off) s += t;
    }
    __shared__ int ws[16];
    if (lane == 63) ws[wid] = s;
    __syncthreads();
    if (wid == 0) {
        int w = (lane < 16) ? ws[lane] : 0;
#pragma unroll
        for (int off = 1; off < 16; off <<= 1) {
            int t = __shfl_up(w, off, 64);
            if (lane >= off) w += t;
        }
        if (lane < 16) ws[lane] = w;
    }
    __syncthreads();
    int excl = (wid ? ws[wid - 1] : 0) + s - v;
    subbase[tid] = excl;
    if (tid == 1023) offsets[N] = excl + v;
}

// ---------------------------------------------------------------------------
// One block per sub-slice: LDS counting sort -> contiguous coalesced writes of
// bucket + offsets. No global scatter, no global cursor atomics.
__global__ __launch_bounds__(256)
void csr_sort_kernel(const unsigned int* __restrict__ subL, const int* __restrict__ tail2,
                     const int* __restrict__ subbase, int* __restrict__ offsets,
                     int* __restrict__ bucket, int N) {
    const int k = blockIdx.x;
    const int tid = threadIdx.x, lane = tid & 63, wid = tid >> 6;
    const int len = min(tail2[k], CAP2);
    const int base = subbase[k];
    const int lo = (int)(((long long)k * N + 1023) >> 10);
    const int hi = (int)(((long long)(k + 1) * N + 1023) >> 10);
    const int nn = hi - lo;  // <= 128
    __shared__ int cnt[128], loff[128], wsum[4];
    __shared__ unsigned int sorted[CAP2];
    const unsigned int* src = subL + (size_t)k * CAP2;

    if (tid < 128) cnt[tid] = 0;
    __syncthreads();
    for (int i = tid; i < len; i += 256) atomicAdd(&cnt[src[i] >> 25], 1);
    __syncthreads();
    // exclusive scan of cnt[0..127] (first 2 waves meaningful)
    int v = (tid < 128) ? cnt[tid] : 0;
    int s = v;
#pragma unroll
    for (int off = 1; off < 64; off <<= 1) {
        int t = __shfl_up(s, off, 64);
        if (lane >= off) s += t;
    }
    if (lane == 63) wsum[wid] = s;
    __syncthreads();
    if (tid < 128) loff[tid] = ((wid == 1) ? wsum[0] : 0) + s - v;
    __syncthreads();
    if (tid < nn) offsets[lo + tid] = base + loff[tid];
    if (tid < 128) cnt[tid] = 0;
    __syncthreads();
    for (int i = tid; i < len; i += 256) {
        unsigned int e = src[i];
        int ld = e >> 25;
        int pos = loff[ld] + atomicAdd(&cnt[ld], 1);
        sorted[pos] = e & 0x1FFFFFFu;
    }
    __syncthreads();
    for (int i = tid; i < len; i += 256) bucket[base + i] = (int)sorted[i];
}

// ---------------------------------------------------------------------------
// pre[n] = bf16( (1+eps)*h[n] + sum_{e in in(n)} relu(h[src_e] + comb[c_e]) )
// One WAVE per node: quad q handles edges beg+8i+q and beg+8i+4+q (16 loads in
// flight), lanes ln cover d-range; cross-quad shfl reduce at the end.
__global__ __launch_bounds__(256)
void gather_reduce_kernel(const int* __restrict__ offsets, const int* __restrict__ bucket,
                          const unsigned short* __restrict__ comb,
                          const unsigned short* __restrict__ hb,
                          const float* __restrict__ eps_l,
                          unsigned short* __restrict__ pre, int N) {
    const int node = (blockIdx.x * 256 + threadIdx.x) >> 6;
    if (node >= N) return;
    const int lane = threadIdx.x & 63;
    const int q = lane >> 4, ln = lane & 15;
    const int d0 = ln * 8;

    union U8 { int4 i; unsigned short u[8]; };
    const int beg = offsets[node], end = offsets[node + 1];

    float a[8];
#pragma unroll
    for (int j = 0; j < 8; ++j) a[j] = 0.f;

    for (int base = beg; base < end; base += 8) {
        int e0 = base + q;
        int e1 = base + 4 + q;
        int pk0 = bucket[min(e0, end - 1)];
        int pk1 = bucket[min(e1, end - 1)];
        U8 h0, c0, h1, c1;
        h0.i = *(const int4*)(hb + (size_t)(pk0 & 0x1FFFF) * D + d0);
        c0.i = *(const int4*)(comb + (size_t)(pk0 >> 17) * D + d0);
        h1.i = *(const int4*)(hb + (size_t)(pk1 & 0x1FFFF) * D + d0);
        c1.i = *(const int4*)(comb + (size_t)(pk1 >> 17) * D + d0);
        if (e0 < end) {
#pragma unroll
            for (int j = 0; j < 8; ++j) a[j] += fmaxf(bf2f(h0.u[j]) + bf2f(c0.u[j]), 0.0f);
        }
        if (e1 < end) {
#pragma unroll
            for (int j = 0; j < 8; ++j) a[j] += fmaxf(bf2f(h1.u[j]) + bf2f(c1.u[j]), 0.0f);
        }
    }
    // reduce across the 4 quads (lanes ln, ln+16, ln+32, ln+48 hold partials)
#pragma unroll
    for (int j = 0; j < 8; ++j) {
        a[j] += __shfl_xor(a[j], 16, 64);
        a[j] += __shfl_xor(a[j], 32, 64);
    }
    if (q == 0) {
        const float s = 1.0f + eps_l[0];
        U8 hv; hv.i = *(const int4*)(hb + (size_t)node * D + d0);
        U8 o;
#pragma unroll
        for (int j = 0; j < 8; ++j) o.u[j] = f2bf(a[j] + s * bf2f(hv.u[j]));
        *(int4*)(pre + (size_t)node * D + d0) = o.i;
    }
}

// ---------------------------------------------------------------------------
// MFMA GEMM, B staged in LDS (2 x 32KB phases), A prefetched; fused stats.
template <int K, int NCOLS, int TRANSFORM, int OUTBF>
__global__ __launch_bounds__(256)
void mfma_gemm_kernel(const unsigned short* __restrict__ A,
                      const unsigned short* __restrict__ Wp,
                      const float* __restrict__ bias,
                      const float* __restrict__ tscale, const float* __restrict__ tshift,
                      unsigned short* __restrict__ Cbf, float* __restrict__ Cf,
                      float* __restrict__ partial, int M) {
    constexpr int NT = NCOLS / 16;
    constexpr int NCHUNK = K / 32;
    constexpr int CPP = NCHUNK / 2;
    __shared__ unsigned short Ws[16384];
    __shared__ float red[NCOLS * 2];

    const int tid = threadIdx.x;
    const int wave = tid >> 6, lane = tid & 63;
    const int quad = lane >> 4, ln = lane & 15;
    const int m_base = blockIdx.x * 64 + wave * 16;
    int arow = m_base + ln;
    if (arow >= M) arow = M - 1;
    const int kq = quad * 8;

    int4 araw[NCHUNK];
#pragma unroll
    for (int c = 0; c < NCHUNK; ++c)
        araw[c] = *(const int4*)(A + (size_t)arow * K + c * 32 + kq);

    for (int i = tid; i < NCOLS * 2; i += 256) red[i] = 0.f;

    floatx4 acc[NT];
#pragma unroll
    for (int t = 0; t < NT; ++t) acc[t] = (floatx4){0.f, 0.f, 0.f, 0.f};

#pragma unroll
    for (int ph = 0; ph < 2; ++ph) {
        if (ph) __syncthreads();
#pragma unroll
        for (int i = 0; i < 16384; i += 2048)
            *(int4*)&Ws[i + tid * 8] = *(const int4*)&Wp[ph * 16384 + i + tid * 8];
        __syncthreads();
#pragma unroll
        for (int cc = 0; cc < CPP; ++cc) {
            const int c = ph * CPP + cc;
            short8 afrag;
            if constexpr (TRANSFORM) {
                union { int4 i; unsigned short u[8]; } raw;
                raw.i = araw[c];
                const int kb = c * 32 + kq;
                float4 sc0 = *(const float4*)(tscale + kb);
                float4 sc1 = *(const float4*)(tscale + kb + 4);
                float4 sh0 = *(const float4*)(tshift + kb);
                float4 sh1 = *(const float4*)(tshift + kb + 4);
                union { short8 v; unsigned short u[8]; } au;
                au.u[0] = f2bf(fmaxf(bf2f(raw.u[0]) * sc0.x + sh0.x, 0.f));
                au.u[1] = f2bf(fmaxf(bf2f(raw.u[1]) * sc0.y + sh0.y, 0.f));
                au.u[2] = f2bf(fmaxf(bf2f(raw.u[2]) * sc0.z + sh0.z, 0.f));
                au.u[3] = f2bf(fmaxf(bf2f(raw.u[3]) * sc0.w + sh0.w, 0.f));
                au.u[4] = f2bf(fmaxf(bf2f(raw.u[4]) * sc1.x + sh1.x, 0.f));
                au.u[5] = f2bf(fmaxf(bf2f(raw.u[5]) * sc1.y + sh1.y, 0.f));
                au.u[6] = f2bf(fmaxf(bf2f(raw.u[6]) * sc1.z + sh1.z, 0.f));
                au.u[7] = f2bf(fmaxf(bf2f(raw.u[7]) * sc1.w + sh1.w, 0.f));
                afrag = au.v;
            } else {
                afrag = __builtin_bit_cast(short8, araw[c]);
            }
#pragma unroll
            for (int t = 0; t < NT; ++t) {
                short8 bfrag = *(const short8*)&Ws[(((cc * NT) + t) << 9) + lane * 8];
                acc[t] = __builtin_amdgcn_mfma_f32_16x16x32_bf16(afrag, bfrag, acc[t], 0, 0, 0);
            }
        }
    }

#pragma unroll
    for (int t = 0; t < NT; ++t) {
        int col = t * 16 + ln;
        float bv = bias[col];
        float sv = 0.f, qv = 0.f;
#pragma unroll
        for (int r = 0; r < 4; ++r) {
            int row = m_base + quad * 4 + r;
            if (row < M) {
                float v = acc[t][r] + bv;
                sv += v; qv += v * v;
                if constexpr (OUTBF) Cbf[(size_t)row * NCOLS + col] = f2bf(v);
                else                 Cf[(size_t)row * NCOLS + col] = v;
            }
        }
        sv += __shfl_xor(sv, 16, 64); sv += __shfl_xor(sv, 32, 64);
        qv += __shfl_xor(qv, 16, 64); qv += __shfl_xor(qv, 32, 64);
        if (quad == 0) {
            atomicAdd(&red[col], sv);
            atomicAdd(&red[NCOLS + col], qv);
        }
    }
    __syncthreads();
    float* pout = partial + (size_t)blockIdx.x * (NCOLS * 2);
    for (int i = tid; i < NCOLS * 2; i += 256) pout[i] = red[i];
}

// ---------------------------------------------------------------------------
template <int NCOLS>
__global__ __launch_bounds__(256)
void reduce_stats_kernel(const float* __restrict__ partial, int nb,
                         const float* __restrict__ g, const float* __restrict__ b,
                         float* __restrict__ scale, float* __restrict__ shift, float invN) {
    const int col = blockIdx.x;
    const int tid = threadIdx.x;
    float s = 0.f, q = 0.f;
    for (int bb = tid; bb < nb; bb += 256) {
        const float* p = partial + (size_t)bb * (NCOLS * 2);
        s += p[col];
        q += p[NCOLS + col];
    }
#pragma unroll
    for (int off = 32; off > 0; off >>= 1) {
        s += __shfl_xor(s, off, 64);
        q += __shfl_xor(q, off, 64);
    }
    __shared__ float ws[4], wq[4];
    if ((tid & 63) == 0) { ws[tid >> 6] = s; wq[tid >> 6] = q; }
    __syncthreads();
    if (tid == 0) {
        s = ws[0] + ws[1] + ws[2] + ws[3];
        q = wq[0] + wq[1] + wq[2] + wq[3];
        float mean = s * invN;
        float var = q * invN - mean * mean;
        float inv = 1.0f / sqrtf(var + BN_EPS);
        float sc = g[col] * inv;
        scale[col] = sc;
        shift[col] = b[col] - mean * sc;
    }
}

// ---------------------------------------------------------------------------
// Reads bf16 raw out2. mode 0: hb = bf16(relu(bn(x))); mode 1: h = bn(x) fp32.
__global__ void bn_apply_kernel(const unsigned short* __restrict__ Xb,
                                float* __restrict__ Yf, unsigned short* __restrict__ Yb,
                                const float* __restrict__ scale, const float* __restrict__ shift,
                                int N, int mode) {
    int gid = blockIdx.x * blockDim.x + threadIdx.x;
    int node = gid >> 5;
    if (node >= N) return;
    int d0 = (gid & 31) * 4;
    ushort4 b = *(const ushort4*)(Xb + (size_t)node * D + d0);
    float4 v;
    v.x = bf2f(b.x); v.y = bf2f(b.y); v.z = bf2f(b.z); v.w = bf2f(b.w);
    float4 sc = *(const float4*)(scale + d0);
    float4 sh = *(const float4*)(shift + d0);
    float4 o;
    o.x = v.x * sc.x + sh.x;
    o.y = v.y * sc.y + sh.y;
    o.z = v.z * sc.z + sh.z;
    o.w = v.w * sc.w + sh.w;
    if (mode == 0) {
        ushort4 ob;
        ob.x = f2bf(fmaxf(o.x, 0.f));
        ob.y = f2bf(fmaxf(o.y, 0.f));
        ob.z = f2bf(fmaxf(o.z, 0.f));
        ob.w = f2bf(fmaxf(o.w, 0.f));
        *(ushort4*)(Yb + (size_t)node * D + d0) = ob;
    } else {
        *(float4*)(Yf + (size_t)node * D + d0) = o;
    }
}

// ---------------------------------------------------------------------------
extern "C" void kernel_launch(void* const* d_in, const int* in_sizes, int n_in,
                              void* d_out, int out_size, void* d_ws, size_t ws_size,
                              hipStream_t stream) {
    const int*   x        = (const int*)d_in[0];
    const int*   z        = (const int*)d_in[1];
    const int*   ei       = (const int*)d_in[2];
    const int*   ea       = (const int*)d_in[3];
    const float* atom_emb = (const float*)d_in[4];
    const float* z_emb    = (const float*)d_in[5];
    const float* bond_emb = (const float*)d_in[6];
    const float* eps      = (const float*)d_in[7];
    const float* W1       = (const float*)d_in[8];
    const float* b1       = (const float*)d_in[9];
    const float* g1       = (const float*)d_in[10];
    const float* be1      = (const float*)d_in[11];
    const float* W2       = (const float*)d_in[12];
    const float* b2       = (const float*)d_in[13];
    const float* bng      = (const float*)d_in[14];
    const float* bnb      = (const float*)d_in[15];

    const int N = in_sizes[1];
    const int E = in_sizes[3] / 3;

    float* h = (float*)d_out;  // final [N,128] fp32

    const int ngb = (N + 63) / 64;   // GEMM grid
    const unsigned long long magic = ((1ULL << 44) / (unsigned int)N) + 1;  // exact for x < 2^27

    char* ws = (char*)d_ws;
    size_t off = 0;
    auto alloc = [&](size_t bytes) { void* p = ws + off; off += (bytes + 255) & ~(size_t)255; return p; };
    unsigned short* pre_bf = (unsigned short*)alloc((size_t)N * D * 2);      // 25.6 MB
    unsigned short* out2_bf = pre_bf;            // gemm2 raw output (pre is dead by then)
    unsigned short* out1_bf = (unsigned short*)alloc((size_t)N * 2 * D * 2); // 51.2 MB
    unsigned short* hb      = (unsigned short*)alloc((size_t)N * D * 2);     // 25.6 MB
    int* offsets = (int*)alloc((size_t)(N + 1) * 4);
    int* bucket  = (int*)alloc((size_t)E * 4);
    unsigned int* subL = (unsigned int*)alloc((size_t)NSUB * CAP2 * 4); // 8 MB
    int* subbase = (int*)alloc(NSUB * 4);
    float* stats = (float*)alloc(1024 * 4);
    float* partial1 = (float*)alloc((size_t)ngb * 512 * 4);  // 3.2 MB
    float* partial2 = (float*)alloc((size_t)ngb * 256 * 4);  // 1.6 MB
    unsigned short* w1p  = (unsigned short*)alloc((size_t)2 * D * 2 * D * 2);
    unsigned short* w2p  = (unsigned short*)alloc((size_t)2 * 2 * D * D * 2);
    unsigned short* comb = (unsigned short*)alloc((size_t)2 * 216 * D * 2);
    // transient tail2 aliases out1_bf (dead until first GEMM1 write)
    int* tail2 = (int*)out1_bf;   // 1024 ints

    float* scale1 = stats;          // 256
    float* shift1 = stats + 256;    // 256
    float* scale2 = stats + 512;    // 128
    float* shift2 = stats + 640;    // 128

    const float invN = 1.0f / (float)N;
    const int ntiles = (E + 4095) / 4096;
    const int nbNode = (N * 32 + 255) / 256;

    // --- CSR build: single-pass 1024-way partition -> subscan -> LDS sort ---
    hipMemsetAsync(tail2, 0, NSUB * sizeof(int), stream);
    partition_kernel<<<256, 256, 0, stream>>>(ei, ea, subL, tail2, E, N, magic, ntiles, 256);
    subscan_kernel<<<1, 1024, 0, stream>>>(tail2, subbase, offsets, N);
    csr_sort_kernel<<<NSUB, 256, 0, stream>>>(subL, tail2, subbase, offsets, bucket, N);

    // --- merged setup: node_init + comb + pack_w1 + pack_w2 ---
    setup_kernel<<<nbNode + 216 + 256 + 256, 256, 0, stream>>>(
        x, z, atom_emb, z_emb, hb, N, nbNode, bond_emb, comb, W1, w1p, W2, w2p);

    for (int l = 0; l < 2; ++l) {
        gather_reduce_kernel<<<(N * 64 + 255) / 256, 256, 0, stream>>>(
            offsets, bucket, comb + (size_t)l * 216 * D, hb, eps + l, pre_bf, N);

        mfma_gemm_kernel<128, 256, 0, 1><<<ngb, 256, 0, stream>>>(
            pre_bf, w1p + (size_t)l * D * 2 * D, b1 + (size_t)l * 2 * D,
            nullptr, nullptr, out1_bf, nullptr, partial1, N);
        reduce_stats_kernel<256><<<256, 256, 0, stream>>>(
            partial1, ngb, g1 + (size_t)l * 2 * D, be1 + (size_t)l * 2 * D,
            scale1, shift1, invN);

        // raw out2 in bf16 for both layers (stats computed from fp32 acc pre-round)
        mfma_gemm_kernel<256, 128, 1, 1><<<ngb, 256, 0, stream>>>(
            out1_bf, w2p + (size_t)l * 2 * D * D, b2 + (size_t)l * D,
            scale1, shift1, out2_bf, nullptr, partial2, N);
        reduce_stats_kernel<128><<<128, 256, 0, stream>>>(
            partial2, ngb, bng + (size_t)l * D, bnb + (size_t)l * D,
            scale2, shift2, invN);

        bn_apply_kernel<<<(N * 32 + 255) / 256, 256, 0, stream>>>(
            out2_bf, h, hb, scale2, shift2, N, l == 0 ? 0 : 1);
    }
}

// Round 4
// 537.887 us; speedup vs baseline: 1.0684x; 1.0379x over previous
//
#include <hip/hip_runtime.h>

#define D 128
#define BN_EPS 1e-5f
#define NSUB 1024
#define CAP2 2048

typedef __attribute__((ext_vector_type(8))) short short8;   // 8 x bf16 (4 VGPRs)
typedef __attribute__((ext_vector_type(4))) float floatx4;  // MFMA accumulator

__device__ __forceinline__ float bf2f(unsigned short u) {
    unsigned int x = ((unsigned int)u) << 16;
    return __builtin_bit_cast(float, x);
}
__device__ __forceinline__ unsigned short f2bf(float f) {
    unsigned int x = __builtin_bit_cast(unsigned int, f);
    x = x + 0x7FFFu + ((x >> 16) & 1u);  // round-to-nearest-even
    return (unsigned short)(x >> 16);
}
// exact floor(x / N) for x < 2^27 via host magic M = 2^44/N + 1 (N < 2^17)
__device__ __forceinline__ int magdiv(unsigned int x, unsigned long long magic) {
    return (int)(((unsigned long long)x * magic) >> 44);
}

// ---------------------------------------------------------------------------
// Merged setup: node_init + comb(fp32) + pack_w1 + pack_w2.
__global__ __launch_bounds__(256)
void setup_kernel(const int* __restrict__ x, const int* __restrict__ z,
                  const float* __restrict__ atom_emb, const float* __restrict__ z_emb,
                  unsigned short* __restrict__ hb, int N, int nbNode,
                  const float* __restrict__ bond_emb, float* __restrict__ comb,
                  const float* __restrict__ W1, unsigned short* __restrict__ w1p,
                  const float* __restrict__ W2, unsigned short* __restrict__ w2p) {
    const int b = blockIdx.x;
    const int tid = threadIdx.x;
    if (b < nbNode) {
        // ---- node_init: hb0 = bf16( sum_f atom_emb[f,x[n,f],:] + z_emb[z[n],:] )
        int gid = b * 256 + tid;
        int node = gid >> 5;
        if (node >= N) return;
        int d0 = (gid & 31) * 4;
        float4 acc = *(const float4*)(z_emb + (size_t)z[node] * D + d0);
#pragma unroll
        for (int f = 0; f < 9; ++f) {
            int v = x[node * 9 + f];
            const float4 t = *(const float4*)(atom_emb + (size_t)(f * 119 + v) * D + d0);
            acc.x += t.x; acc.y += t.y; acc.z += t.z; acc.w += t.w;
        }
        ushort4 o;
        o.x = f2bf(acc.x); o.y = f2bf(acc.y); o.z = f2bf(acc.z); o.w = f2bf(acc.w);
        *(ushort4*)(hb + (size_t)node * D + d0) = o;
    } else if (b < nbNode + 216) {
        // ---- comb[layer][c][d] = b0[a0][d]+b1[a1][d]+b2[a2][d]  (fp32, L2-resident)
        int t = (b - nbNode) * 256 + tid;
        int layer = t / (216 * D);
        int idx = t - layer * (216 * D);
        int c = idx >> 7, d = idx & 127;
        int a0 = c / 36, a1 = (c / 6) % 6, a2 = c % 6;
        const float* bb = bond_emb + (size_t)layer * 3 * 6 * D;
        float v = bb[(0 * 6 + a0) * D + d] + bb[(1 * 6 + a1) * D + d] + bb[(2 * 6 + a2) * D + d];
        comb[(size_t)layer * 216 * D + idx] = v;
    } else {
        // ---- pack W [K][NCOLS] fp32 row-major -> fragment-linear bf16
        int isW2 = (b >= nbNode + 216 + 256);
        int t = (b - nbNode - 216 - (isW2 ? 256 : 0)) * 256 + tid;
        int layer = t >> 15;           // total = 32768 per layer for both
        int idx = t & 32767;
        int logN = isW2 ? 7 : 8;
        int NCOLS = 1 << logN;
        int k = idx >> logN, n = idx & (NCOLS - 1);
        int k0 = k >> 5, kq = k & 31, q = kq >> 3, j = kq & 7;
        int tt = n >> 4, ln = n & 15;
        size_t dest = (((size_t)k0 * (NCOLS >> 4) + tt) << 9) + ((q << 4) + ln) * 8 + j;
        const float* W = (isW2 ? W2 : W1) + (size_t)layer * 32768;
        unsigned short* Wp = (isW2 ? w2p : w1p) + (size_t)layer * 32768;
        Wp[dest] = f2bf(W[idx]);
    }
}

// ---------------------------------------------------------------------------
// Single-pass 1024-way partition: edges -> 1024 sub-slice lists directly.
// Packed entry: src(17) | comb_idx<<17 (8) | local_dst<<25 (7).
__global__ __launch_bounds__(256)
void partition_kernel(const int* __restrict__ ei, const int* __restrict__ ea,
                      unsigned int* __restrict__ subL, int* __restrict__ tail2,
                      int E, int N, unsigned long long magic, int ntiles, int nblocks) {
    __shared__ int lcnt[1024], lbase[1024];
    const int tid = threadIdx.x;
    for (int tile = blockIdx.x; tile < ntiles; tile += nblocks) {
        const int tb = tile * 4096;
#pragma unroll
        for (int i = 0; i < 4; ++i) lcnt[tid + i * 256] = 0;
        __syncthreads();
        int sub[16];
        unsigned int entry[16];
#pragma unroll
        for (int j = 0; j < 16; ++j) {
            int e = tb + j * 256 + tid;
            if (e < E) {
                int dst = ei[E + e];
                int c = (ea[3 * e] * 6 + ea[3 * e + 1]) * 6 + ea[3 * e + 2];
                int k = magdiv((unsigned)dst * 1024u, magic);
                int lo = (int)(((long long)k * N + 1023) >> 10);
                sub[j] = k;
                entry[j] = (unsigned int)ei[e] | ((unsigned int)c << 17) |
                           ((unsigned int)(dst - lo) << 25);
                atomicAdd(&lcnt[k], 1);
            } else {
                sub[j] = -1;
            }
        }
        __syncthreads();
#pragma unroll
        for (int i = 0; i < 4; ++i) {
            int k = tid + i * 256;
            int c = lcnt[k];
            if (c) lbase[k] = atomicAdd(&tail2[k], c);
            lcnt[k] = 0;
        }
        __syncthreads();
#pragma unroll
        for (int j = 0; j < 16; ++j) {
            if (sub[j] >= 0) {
                int k = sub[j];
                int pos = lbase[k] + atomicAdd(&lcnt[k], 1);
                if (pos < CAP2) subL[(size_t)k * CAP2 + pos] = entry[j];
            }
        }
        __syncthreads();
    }
}

// ---------------------------------------------------------------------------
// Exclusive scan of 1024 sub-slice tails -> subbase; offsets[N] = E.
__global__ __launch_bounds__(1024)
void subscan_kernel(const int* __restrict__ tail2, int* __restrict__ subbase,
                    int* __restrict__ offsets, int N) {
    const int tid = threadIdx.x, lane = tid & 63, wid = tid >> 6;
    int v = min(tail2[tid], CAP2);
    int s = v;
#pragma unroll
    for (int off = 1; off < 64; off <<= 1) {
        int t = __shfl_up(s, off, 64);
        if (lane >= off) s += t;
    }
    __shared__ int ws[16];
    if (lane == 63) ws[wid] = s;
    __syncthreads();
    if (wid == 0) {
        int w = (lane < 16) ? ws[lane] : 0;
#pragma unroll
        for (int off = 1; off < 16; off <<= 1) {
            int t = __shfl_up(w, off, 64);
            if (lane >= off) w += t;
        }
        if (lane < 16) ws[lane] = w;
    }
    __syncthreads();
    int excl = (wid ? ws[wid - 1] : 0) + s - v;
    subbase[tid] = excl;
    if (tid == 1023) offsets[N] = excl + v;
}

// ---------------------------------------------------------------------------
// One block per sub-slice: LDS counting sort -> contiguous coalesced writes of
// bucket + offsets. No global scatter, no global cursor atomics.
__global__ __launch_bounds__(256)
void csr_sort_kernel(const unsigned int* __restrict__ subL, const int* __restrict__ tail2,
                     const int* __restrict__ subbase, int* __restrict__ offsets,
                     int* __restrict__ bucket, int N) {
    const int k = blockIdx.x;
    const int tid = threadIdx.x, lane = tid & 63, wid = tid >> 6;
    const int len = min(tail2[k], CAP2);
    const int base = subbase[k];
    const int lo = (int)(((long long)k * N + 1023) >> 10);
    const int hi = (int)(((long long)(k + 1) * N + 1023) >> 10);
    const int nn = hi - lo;  // <= 128
    __shared__ int cnt[128], loff[128], wsum[4];
    __shared__ unsigned int sorted[CAP2];
    const unsigned int* src = subL + (size_t)k * CAP2;

    if (tid < 128) cnt[tid] = 0;
    __syncthreads();
    for (int i = tid; i < len; i += 256) atomicAdd(&cnt[src[i] >> 25], 1);
    __syncthreads();
    // exclusive scan of cnt[0..127] (first 2 waves meaningful)
    int v = (tid < 128) ? cnt[tid] : 0;
    int s = v;
#pragma unroll
    for (int off = 1; off < 64; off <<= 1) {
        int t = __shfl_up(s, off, 64);
        if (lane >= off) s += t;
    }
    if (lane == 63) wsum[wid] = s;
    __syncthreads();
    if (tid < 128) loff[tid] = ((wid == 1) ? wsum[0] : 0) + s - v;
    __syncthreads();
    if (tid < nn) offsets[lo + tid] = base + loff[tid];
    if (tid < 128) cnt[tid] = 0;
    __syncthreads();
    for (int i = tid; i < len; i += 256) {
        unsigned int e = src[i];
        int ld = e >> 25;
        int pos = loff[ld] + atomicAdd(&cnt[ld], 1);
        sorted[pos] = e & 0x1FFFFFFu;
    }
    __syncthreads();
    for (int i = tid; i < len; i += 256) bucket[base + i] = (int)sorted[i];
}

// ---------------------------------------------------------------------------
// pre[n] = bf16( (1+eps)*h[n] + sum_{e in in(n)} relu(h[src_e] + comb[c_e]) )
// 16 threads/node, 4-edge unroll (8 loads in flight). comb is fp32 (L2-hot):
// halves the bf16-unpack VALU work per edge.
__global__ __launch_bounds__(256)
void gather_reduce_kernel(const int* __restrict__ offsets, const int* __restrict__ bucket,
                          const float* __restrict__ comb,
                          const unsigned short* __restrict__ hb,
                          const float* __restrict__ eps_l,
                          unsigned short* __restrict__ pre, int N) {
    int gid = blockIdx.x * blockDim.x + threadIdx.x;
    int node = gid >> 4;
    if (node >= N) return;
    int d0 = (gid & 15) * 8;

    union U8 { int4 i; unsigned short u[8]; };
    union C8 { float4 v[2]; float f[8]; };
    float s = 1.0f + eps_l[0];
    float a[8];
    {
        U8 hv; hv.i = *(const int4*)(hb + (size_t)node * D + d0);
#pragma unroll
        for (int j = 0; j < 8; ++j) a[j] = bf2f(hv.u[j]) * s;
    }
    const int beg = offsets[node], end = offsets[node + 1];
    for (int p = beg; p < end; p += 4) {
        int rem = end - p;
        int pk0 = bucket[p];
        int pk1 = bucket[rem > 1 ? p + 1 : p];
        int pk2 = bucket[rem > 2 ? p + 2 : p];
        int pk3 = bucket[rem > 3 ? p + 3 : p];
        U8 h0, h1, h2, h3;
        C8 c0, c1, c2, c3;
        h0.i = *(const int4*)(hb + (size_t)(pk0 & 0x1FFFF) * D + d0);
        c0.v[0] = *(const float4*)(comb + (size_t)(pk0 >> 17) * D + d0);
        c0.v[1] = *(const float4*)(comb + (size_t)(pk0 >> 17) * D + d0 + 4);
        h1.i = *(const int4*)(hb + (size_t)(pk1 & 0x1FFFF) * D + d0);
        c1.v[0] = *(const float4*)(comb + (size_t)(pk1 >> 17) * D + d0);
        c1.v[1] = *(const float4*)(comb + (size_t)(pk1 >> 17) * D + d0 + 4);
        h2.i = *(const int4*)(hb + (size_t)(pk2 & 0x1FFFF) * D + d0);
        c2.v[0] = *(const float4*)(comb + (size_t)(pk2 >> 17) * D + d0);
        c2.v[1] = *(const float4*)(comb + (size_t)(pk2 >> 17) * D + d0 + 4);
        h3.i = *(const int4*)(hb + (size_t)(pk3 & 0x1FFFF) * D + d0);
        c3.v[0] = *(const float4*)(comb + (size_t)(pk3 >> 17) * D + d0);
        c3.v[1] = *(const float4*)(comb + (size_t)(pk3 >> 17) * D + d0 + 4);
#pragma unroll
        for (int j = 0; j < 8; ++j) a[j] += fmaxf(bf2f(h0.u[j]) + c0.f[j], 0.0f);
        if (rem > 1) {
#pragma unroll
            for (int j = 0; j < 8; ++j) a[j] += fmaxf(bf2f(h1.u[j]) + c1.f[j], 0.0f);
        }
        if (rem > 2) {
#pragma unroll
            for (int j = 0; j < 8; ++j) a[j] += fmaxf(bf2f(h2.u[j]) + c2.f[j], 0.0f);
        }
        if (rem > 3) {
#pragma unroll
            for (int j = 0; j < 8; ++j) a[j] += fmaxf(bf2f(h3.u[j]) + c3.f[j], 0.0f);
        }
    }
    U8 o;
#pragma unroll
    for (int j = 0; j < 8; ++j) o.u[j] = f2bf(a[j]);
    *(int4*)(pre + (size_t)node * D + d0) = o.i;
}

// ---------------------------------------------------------------------------
// MFMA GEMM, B staged in LDS (2 x 32KB phases), A prefetched; fused stats.
template <int K, int NCOLS, int TRANSFORM, int OUTBF>
__global__ __launch_bounds__(256)
void mfma_gemm_kernel(const unsigned short* __restrict__ A,
                      const unsigned short* __restrict__ Wp,
                      const float* __restrict__ bias,
                      const float* __restrict__ tscale, const float* __restrict__ tshift,
                      unsigned short* __restrict__ Cbf, float* __restrict__ Cf,
                      float* __restrict__ partial, int M) {
    constexpr int NT = NCOLS / 16;
    constexpr int NCHUNK = K / 32;
    constexpr int CPP = NCHUNK / 2;
    __shared__ unsigned short Ws[16384];
    __shared__ float red[NCOLS * 2];

    const int tid = threadIdx.x;
    const int wave = tid >> 6, lane = tid & 63;
    const int quad = lane >> 4, ln = lane & 15;
    const int m_base = blockIdx.x * 64 + wave * 16;
    int arow = m_base + ln;
    if (arow >= M) arow = M - 1;
    const int kq = quad * 8;

    int4 araw[NCHUNK];
#pragma unroll
    for (int c = 0; c < NCHUNK; ++c)
        araw[c] = *(const int4*)(A + (size_t)arow * K + c * 32 + kq);

    for (int i = tid; i < NCOLS * 2; i += 256) red[i] = 0.f;

    floatx4 acc[NT];
#pragma unroll
    for (int t = 0; t < NT; ++t) acc[t] = (floatx4){0.f, 0.f, 0.f, 0.f};

#pragma unroll
    for (int ph = 0; ph < 2; ++ph) {
        if (ph) __syncthreads();
#pragma unroll
        for (int i = 0; i < 16384; i += 2048)
            *(int4*)&Ws[i + tid * 8] = *(const int4*)&Wp[ph * 16384 + i + tid * 8];
        __syncthreads();
#pragma unroll
        for (int cc = 0; cc < CPP; ++cc) {
            const int c = ph * CPP + cc;
            short8 afrag;
            if constexpr (TRANSFORM) {
                union { int4 i; unsigned short u[8]; } raw;
                raw.i = araw[c];
                const int kb = c * 32 + kq;
                float4 sc0 = *(const float4*)(tscale + kb);
                float4 sc1 = *(const float4*)(tscale + kb + 4);
                float4 sh0 = *(const float4*)(tshift + kb);
                float4 sh1 = *(const float4*)(tshift + kb + 4);
                union { short8 v; unsigned short u[8]; } au;
                au.u[0] = f2bf(fmaxf(bf2f(raw.u[0]) * sc0.x + sh0.x, 0.f));
                au.u[1] = f2bf(fmaxf(bf2f(raw.u[1]) * sc0.y + sh0.y, 0.f));
                au.u[2] = f2bf(fmaxf(bf2f(raw.u[2]) * sc0.z + sh0.z, 0.f));
                au.u[3] = f2bf(fmaxf(bf2f(raw.u[3]) * sc0.w + sh0.w, 0.f));
                au.u[4] = f2bf(fmaxf(bf2f(raw.u[4]) * sc1.x + sh1.x, 0.f));
                au.u[5] = f2bf(fmaxf(bf2f(raw.u[5]) * sc1.y + sh1.y, 0.f));
                au.u[6] = f2bf(fmaxf(bf2f(raw.u[6]) * sc1.z + sh1.z, 0.f));
                au.u[7] = f2bf(fmaxf(bf2f(raw.u[7]) * sc1.w + sh1.w, 0.f));
                afrag = au.v;
            } else {
                afrag = __builtin_bit_cast(short8, araw[c]);
            }
#pragma unroll
            for (int t = 0; t < NT; ++t) {
                short8 bfrag = *(const short8*)&Ws[(((cc * NT) + t) << 9) + lane * 8];
                acc[t] = __builtin_amdgcn_mfma_f32_16x16x32_bf16(afrag, bfrag, acc[t], 0, 0, 0);
            }
        }
    }

#pragma unroll
    for (int t = 0; t < NT; ++t) {
        int col = t * 16 + ln;
        float bv = bias[col];
        float sv = 0.f, qv = 0.f;
#pragma unroll
        for (int r = 0; r < 4; ++r) {
            int row = m_base + quad * 4 + r;
            if (row < M) {
                float v = acc[t][r] + bv;
                sv += v; qv += v * v;
                if constexpr (OUTBF) Cbf[(size_t)row * NCOLS + col] = f2bf(v);
                else                 Cf[(size_t)row * NCOLS + col] = v;
            }
        }
        sv += __shfl_xor(sv, 16, 64); sv += __shfl_xor(sv, 32, 64);
        qv += __shfl_xor(qv, 16, 64); qv += __shfl_xor(qv, 32, 64);
        if (quad == 0) {
            atomicAdd(&red[col], sv);
            atomicAdd(&red[NCOLS + col], qv);
        }
    }
    __syncthreads();
    float* pout = partial + (size_t)blockIdx.x * (NCOLS * 2);
    for (int i = tid; i < NCOLS * 2; i += 256) pout[i] = red[i];
}

// ---------------------------------------------------------------------------
template <int NCOLS>
__global__ __launch_bounds__(256)
void reduce_stats_kernel(const float* __restrict__ partial, int nb,
                         const float* __restrict__ g, const float* __restrict__ b,
                         float* __restrict__ scale, float* __restrict__ shift, float invN) {
    const int col = blockIdx.x;
    const int tid = threadIdx.x;
    float s = 0.f, q = 0.f;
    for (int bb = tid; bb < nb; bb += 256) {
        const float* p = partial + (size_t)bb * (NCOLS * 2);
        s += p[col];
        q += p[NCOLS + col];
    }
#pragma unroll
    for (int off = 32; off > 0; off >>= 1) {
        s += __shfl_xor(s, off, 64);
        q += __shfl_xor(q, off, 64);
    }
    __shared__ float ws[4], wq[4];
    if ((tid & 63) == 0) { ws[tid >> 6] = s; wq[tid >> 6] = q; }
    __syncthreads();
    if (tid == 0) {
        s = ws[0] + ws[1] + ws[2] + ws[3];
        q = wq[0] + wq[1] + wq[2] + wq[3];
        float mean = s * invN;
        float var = q * invN - mean * mean;
        float inv = 1.0f / sqrtf(var + BN_EPS);
        float sc = g[col] * inv;
        scale[col] = sc;
        shift[col] = b[col] - mean * sc;
    }
}

// ---------------------------------------------------------------------------
// Reads bf16 raw out2. mode 0: hb = bf16(relu(bn(x))); mode 1: h = bn(x) fp32.
__global__ void bn_apply_kernel(const unsigned short* __restrict__ Xb,
                                float* __restrict__ Yf, unsigned short* __restrict__ Yb,
                                const float* __restrict__ scale, const float* __restrict__ shift,
                                int N, int mode) {
    int gid = blockIdx.x * blockDim.x + threadIdx.x;
    int node = gid >> 5;
    if (node >= N) return;
    int d0 = (gid & 31) * 4;
    ushort4 b = *(const ushort4*)(Xb + (size_t)node * D + d0);
    float4 v;
    v.x = bf2f(b.x); v.y = bf2f(b.y); v.z = bf2f(b.z); v.w = bf2f(b.w);
    float4 sc = *(const float4*)(scale + d0);
    float4 sh = *(const float4*)(shift + d0);
    float4 o;
    o.x = v.x * sc.x + sh.x;
    o.y = v.y * sc.y + sh.y;
    o.z = v.z * sc.z + sh.z;
    o.w = v.w * sc.w + sh.w;
    if (mode == 0) {
        ushort4 ob;
        ob.x = f2bf(fmaxf(o.x, 0.f));
        ob.y = f2bf(fmaxf(o.y, 0.f));
        ob.z = f2bf(fmaxf(o.z, 0.f));
        ob.w = f2bf(fmaxf(o.w, 0.f));
        *(ushort4*)(Yb + (size_t)node * D + d0) = ob;
    } else {
        *(float4*)(Yf + (size_t)node * D + d0) = o;
    }
}

// ---------------------------------------------------------------------------
extern "C" void kernel_launch(void* const* d_in, const int* in_sizes, int n_in,
                              void* d_out, int out_size, void* d_ws, size_t ws_size,
                              hipStream_t stream) {
    const int*   x        = (const int*)d_in[0];
    const int*   z        = (const int*)d_in[1];
    const int*   ei       = (const int*)d_in[2];
    const int*   ea       = (const int*)d_in[3];
    const float* atom_emb = (const float*)d_in[4];
    const float* z_emb    = (const float*)d_in[5];
    const float* bond_emb = (const float*)d_in[6];
    const float* eps      = (const float*)d_in[7];
    const float* W1       = (const float*)d_in[8];
    const float* b1       = (const float*)d_in[9];
    const float* g1       = (const float*)d_in[10];
    const float* be1      = (const float*)d_in[11];
    const float* W2       = (const float*)d_in[12];
    const float* b2       = (const float*)d_in[13];
    const float* bng      = (const float*)d_in[14];
    const float* bnb      = (const float*)d_in[15];

    const int N = in_sizes[1];
    const int E = in_sizes[3] / 3;

    float* h = (float*)d_out;  // final [N,128] fp32

    const int ngb = (N + 63) / 64;   // GEMM grid
    const unsigned long long magic = ((1ULL << 44) / (unsigned int)N) + 1;  // exact for x < 2^27

    char* ws = (char*)d_ws;
    size_t off = 0;
    auto alloc = [&](size_t bytes) { void* p = ws + off; off += (bytes + 255) & ~(size_t)255; return p; };
    unsigned short* pre_bf = (unsigned short*)alloc((size_t)N * D * 2);      // 25.6 MB
    unsigned short* out2_bf = pre_bf;            // gemm2 raw output (pre is dead by then)
    unsigned short* out1_bf = (unsigned short*)alloc((size_t)N * 2 * D * 2); // 51.2 MB
    unsigned short* hb      = (unsigned short*)alloc((size_t)N * D * 2);     // 25.6 MB
    int* offsets = (int*)alloc((size_t)(N + 1) * 4);
    int* bucket  = (int*)alloc((size_t)E * 4);
    unsigned int* subL = (unsigned int*)alloc((size_t)NSUB * CAP2 * 4); // 8 MB
    int* subbase = (int*)alloc(NSUB * 4);
    float* stats = (float*)alloc(1024 * 4);
    float* partial1 = (float*)alloc((size_t)ngb * 512 * 4);  // 3.2 MB
    float* partial2 = (float*)alloc((size_t)ngb * 256 * 4);  // 1.6 MB
    unsigned short* w1p  = (unsigned short*)alloc((size_t)2 * D * 2 * D * 2);
    unsigned short* w2p  = (unsigned short*)alloc((size_t)2 * 2 * D * D * 2);
    float* comb = (float*)alloc((size_t)2 * 216 * D * 4);    // fp32 comb, 221 KB
    // transient tail2 aliases out1_bf (dead until first GEMM1 write)
    int* tail2 = (int*)out1_bf;   // 1024 ints

    float* scale1 = stats;          // 256
    float* shift1 = stats + 256;    // 256
    float* scale2 = stats + 512;    // 128
    float* shift2 = stats + 640;    // 128

    const float invN = 1.0f / (float)N;
    const int ntiles = (E + 4095) / 4096;
    const int nbNode = (N * 32 + 255) / 256;

    // --- CSR build: single-pass 1024-way partition -> subscan -> LDS sort ---
    hipMemsetAsync(tail2, 0, NSUB * sizeof(int), stream);
    partition_kernel<<<256, 256, 0, stream>>>(ei, ea, subL, tail2, E, N, magic, ntiles, 256);
    subscan_kernel<<<1, 1024, 0, stream>>>(tail2, subbase, offsets, N);
    csr_sort_kernel<<<NSUB, 256, 0, stream>>>(subL, tail2, subbase, offsets, bucket, N);

    // --- merged setup: node_init + comb + pack_w1 + pack_w2 ---
    setup_kernel<<<nbNode + 216 + 256 + 256, 256, 0, stream>>>(
        x, z, atom_emb, z_emb, hb, N, nbNode, bond_emb, comb, W1, w1p, W2, w2p);

    for (int l = 0; l < 2; ++l) {
        gather_reduce_kernel<<<(N * 16 + 255) / 256, 256, 0, stream>>>(
            offsets, bucket, comb + (size_t)l * 216 * D, hb, eps + l, pre_bf, N);

        mfma_gemm_kernel<128, 256, 0, 1><<<ngb, 256, 0, stream>>>(
            pre_bf, w1p + (size_t)l * D * 2 * D, b1 + (size_t)l * 2 * D,
            nullptr, nullptr, out1_bf, nullptr, partial1, N);
        reduce_stats_kernel<256><<<256, 256, 0, stream>>>(
            partial1, ngb, g1 + (size_t)l * 2 * D, be1 + (size_t)l * 2 * D,
            scale1, shift1, invN);

        // raw out2 in bf16 for both layers (stats computed from fp32 acc pre-round)
        mfma_gemm_kernel<256, 128, 1, 1><<<ngb, 256, 0, stream>>>(
            out1_bf, w2p + (size_t)l * 2 * D * D, b2 + (size_t)l * D,
            scale1, shift1, out2_bf, nullptr, partial2, N);
        reduce_stats_kernel<128><<<128, 256, 0, stream>>>(
            partial2, ngb, bng + (size_t)l * D, bnb + (size_t)l * D,
            scale2, shift2, invN);

        bn_apply_kernel<<<(N * 32 + 255) / 256, 256, 0, stream>>>(
            out2_bf, h, hb, scale2, shift2, N, l == 0 ? 0 : 1);
    }
}